// Round 20
// baseline (235.587 us; speedup 1.0000x reference)
//
#include <hip/hip_runtime.h>
#include <stdint.h>

typedef unsigned short u16;
typedef __attribute__((ext_vector_type(8))) short bf16x8;
typedef __attribute__((ext_vector_type(8))) u16 u16x8;
typedef __attribute__((ext_vector_type(4))) u16 u16x4;
typedef __attribute__((ext_vector_type(4))) float f32x4;
typedef __attribute__((ext_vector_type(16))) float f32x16;

#define B_ 16
#define S_ 1024
#define D_ 768
#define H_ 12

__device__ __forceinline__ float bf2f(u16 u) {
  unsigned int x = ((unsigned int)u) << 16;
  float f;
  __builtin_memcpy(&f, &x, 4);
  return f;
}
__device__ __forceinline__ u16 f2bf(float f) {
  unsigned int x;
  __builtin_memcpy(&x, &f, 4);
  x += 0x7fffu + ((x >> 16) & 1u);
  return (u16)(x >> 16);
}
__device__ __forceinline__ unsigned cvt_pk_bf16(float lo, float hi) {
  unsigned r;
  asm("v_cvt_pk_bf16_f32 %0, %1, %2" : "=v"(r) : "v"(lo), "v"(hi));
  return r;  // lo -> bits[15:0], hi -> bits[31:16]
}

#define MFMA16(a, b, c) __builtin_amdgcn_mfma_f32_16x16x32_bf16((a), (b), (c), 0, 0, 0)
#define MFMA32(a, b, c) __builtin_amdgcn_mfma_f32_32x32x16_bf16((a), (b), (c), 0, 0, 0)

#define GLD16(g, l)                                              \
  __builtin_amdgcn_global_load_lds(                              \
      (const __attribute__((address_space(1))) void*)(g),        \
      (__attribute__((address_space(3))) void*)(l), 16, 0, 0)

// ---------------------------------------------------------------------------
// Fused prologue: f32->bf16 convert of x + two transpose-convert weights.
// ---------------------------------------------------------------------------
__global__ __launch_bounds__(256) void prep(const float* __restrict__ x,
                                            u16* __restrict__ xb,
                                            const float* __restrict__ Wqkv,
                                            u16* __restrict__ WqkvT,
                                            const float* __restrict__ Wo,
                                            u16* __restrict__ WoT) {
  __shared__ u16 tt[32][33];
  const int gx = blockIdx.x;
  const int tid = threadIdx.x;
  if (gx < 6144) {  // cvt x: 16384*768/8 = 1,572,864 vec8 elems, exact
    const int i = gx * 256 + tid;
    const float4 a = *(const float4*)(x + (size_t)i * 8);
    const float4 b = *(const float4*)(x + (size_t)i * 8 + 4);
    u16x8 o;
    o[0] = f2bf(a.x); o[1] = f2bf(a.y); o[2] = f2bf(a.z); o[3] = f2bf(a.w);
    o[4] = f2bf(b.x); o[5] = f2bf(b.y); o[6] = f2bf(b.z); o[7] = f2bf(b.w);
    *(u16x8*)(xb + (size_t)i * 8) = o;
  } else if (gx < 6144 + 1728) {  // Wqkv [768,2304] -> WqkvT [2304,768]
    const int t = gx - 6144;
    const int n0 = (t % 72) * 32, k0 = (t / 72) * 32;
    const int tx = tid & 31, ty = tid >> 5;
#pragma unroll
    for (int i = 0; i < 32; i += 8)
      tt[ty + i][tx] = f2bf(Wqkv[(size_t)(k0 + ty + i) * 2304 + n0 + tx]);
    __syncthreads();
#pragma unroll
    for (int i = 0; i < 32; i += 8)
      WqkvT[(size_t)(n0 + ty + i) * 768 + k0 + tx] = tt[tx][ty + i];
  } else {  // Wo [768,768] -> WoT [768,768]
    const int t = gx - 7872;
    const int n0 = (t % 24) * 32, k0 = (t / 24) * 32;
    const int tx = tid & 31, ty = tid >> 5;
#pragma unroll
    for (int i = 0; i < 32; i += 8)
      tt[ty + i][tx] = f2bf(Wo[(size_t)(k0 + ty + i) * 768 + n0 + tx]);
    __syncthreads();
#pragma unroll
    for (int i = 0; i < 32; i += 8)
      WoT[(size_t)(n0 + ty + i) * 768 + k0 + tx] = tt[tx][ty + i];
  }
}

// ---------------------------------------------------------------------------
// 128x128x64 MFMA GEMM + XCD-stripe schedule (r16 core, proven fastest).
// MODE 0: QKV epilogue -> Q pre-scaled by 0.125*log2(e) (scores land in
//         log2-units so attention uses bare v_exp), K row-major bf16,
//         V^T [B,H,HS,S] bf16 (u16x4-grouped stores).
// MODE 1: f32 row-major Of[M,N].
// ---------------------------------------------------------------------------
template <int MODE>
__global__ __launch_bounds__(256, 2) void gemm_bt(const u16* __restrict__ A,
                                                  const u16* __restrict__ Bt,
                                                  const float* __restrict__ bias,
                                                  u16* __restrict__ O0, u16* __restrict__ O1,
                                                  u16* __restrict__ O2, float* __restrict__ Of,
                                                  int M, int N, int K, int NBT) {
  __shared__ u16 Al[2 * 128 * 64];  // 2 bufs x 16 KB
  __shared__ u16 Bl[2 * 128 * 64];
  const int tid = threadIdx.x;
  const int wid = tid >> 6, lane = tid & 63;
  const int lo = lane & 15, hi = lane >> 4;
  const int wr = wid >> 1, wc = wid & 1;
  const int bid = blockIdx.x;
  const int xcd = bid & 7, idx = bid >> 3;
  const int mb = xcd * 16 + idx / NBT;
  const int nb = idx % NBT;
  const int m0 = mb * 128, n0 = nb * 128;
  const int T = K >> 6;  // 12

  const int sr = lane >> 3;
  const int kk = ((lane & 7) ^ sr) * 8;  // pre-swizzled k element offset
  const u16* const asrc = A + (size_t)(m0 + wid * 8 + sr) * K + kk;
  const u16* const bsrc = Bt + (size_t)(n0 + wid * 8 + sr) * K + kk;

#define STAGE(kt, buf)                                                          \
  do {                                                                          \
    const size_t _k = (size_t)(kt) * 64;                                        \
    GLD16(asrc + _k, (char*)Al + (buf) * 16384 + (wid) * 1024);                 \
    GLD16(asrc + (size_t)32 * K + _k, (char*)Al + (buf) * 16384 + (wid + 4) * 1024);  \
    GLD16(asrc + (size_t)64 * K + _k, (char*)Al + (buf) * 16384 + (wid + 8) * 1024);  \
    GLD16(asrc + (size_t)96 * K + _k, (char*)Al + (buf) * 16384 + (wid + 12) * 1024); \
    GLD16(bsrc + _k, (char*)Bl + (buf) * 16384 + (wid) * 1024);                 \
    GLD16(bsrc + (size_t)32 * K + _k, (char*)Bl + (buf) * 16384 + (wid + 4) * 1024);  \
    GLD16(bsrc + (size_t)64 * K + _k, (char*)Bl + (buf) * 16384 + (wid + 8) * 1024);  \
    GLD16(bsrc + (size_t)96 * K + _k, (char*)Bl + (buf) * 16384 + (wid + 12) * 1024); \
  } while (0)

  f32x4 acc[4][4] = {};

  STAGE(0, 0);
  asm volatile("s_waitcnt vmcnt(0)" ::: "memory");
  __builtin_amdgcn_s_barrier();

  for (int t = 0; t < T; ++t) {
    if (t + 1 < T) STAGE(t + 1, (t + 1) & 1);
    const int cb = (t & 1) * 16384;
    const int swz = (lo & 7) << 4;
    bf16x8 af[4][2], bfv[4][2];
#pragma unroll
    for (int i = 0; i < 4; ++i)
#pragma unroll
      for (int s = 0; s < 2; ++s)
        af[i][s] = *(const bf16x8*)((const char*)Al + cb + (wr * 64 + i * 16 + lo) * 128 +
                                    ((s * 64 + hi * 16) ^ swz));
#pragma unroll
    for (int j = 0; j < 4; ++j)
#pragma unroll
      for (int s = 0; s < 2; ++s)
        bfv[j][s] = *(const bf16x8*)((const char*)Bl + cb + (wc * 64 + j * 16 + lo) * 128 +
                                     ((s * 64 + hi * 16) ^ swz));
    __builtin_amdgcn_s_setprio(1);
#pragma unroll
    for (int i = 0; i < 4; ++i)
#pragma unroll
      for (int j = 0; j < 4; ++j) {
        acc[i][j] = MFMA16(af[i][0], bfv[j][0], acc[i][j]);
        acc[i][j] = MFMA16(af[i][1], bfv[j][1], acc[i][j]);
      }
    __builtin_amdgcn_s_setprio(0);
    if (t + 1 < T) asm volatile("s_waitcnt vmcnt(0)" ::: "memory");
    __builtin_amdgcn_s_barrier();
  }
#undef STAGE
  // Epilogue. C/D: col = lane&15, row = (lane>>4)*4 + r  [verified m89/m91]
  if (MODE == 0 && n0 >= 2 * D_) {
#pragma unroll
    for (int g = 0; g < 4; ++g) {
      const int n = n0 + wc * 64 + g * 16 + lo;
      const float bv = bias[n];
      const int np = n - 2 * D_;
#pragma unroll
      for (int f = 0; f < 4; ++f) {
        const int m = m0 + wr * 64 + f * 16 + hi * 4;
        u16x4 q;
#pragma unroll
        for (int r = 0; r < 4; ++r) q[r] = f2bf(acc[f][g][r] + bv);
        *(u16x4*)&O2[(((size_t)(m >> 10) * H_ + (np >> 6)) * 64 + (np & 63)) * S_ +
                     (m & 1023)] = q;
      }
    }
  } else {
    // Q region: fold attention scale AND log2(e) so scores are log2-units.
    const bool isQ = (MODE == 0) && (n0 < D_);
    const float sc = isQ ? 0.125f * 1.4426950408889634f : 1.0f;
#pragma unroll
    for (int g = 0; g < 4; ++g) {
      const int n = n0 + wc * 64 + g * 16 + lo;
      const float bv = bias[n] * sc;
#pragma unroll
      for (int f = 0; f < 4; ++f) {
#pragma unroll
        for (int r = 0; r < 4; ++r) {
          const int m = m0 + wr * 64 + f * 16 + hi * 4 + r;
          const float fv = acc[f][g][r] * sc + bv;
          if (MODE == 0) {
            const u16 o = f2bf(fv);
            if (n0 < D_) {
              O0[(size_t)m * D_ + n] = o;  // Q (pre-scaled, log2-units)
            } else {
              O1[(size_t)m * D_ + (n - D_)] = o;  // K row-major
            }
          } else {
            Of[(size_t)m * N + n] = fv;  // f32 output
          }
        }
      }
    }
  }
}

// ---------------------------------------------------------------------------
// Flash attention v5 (r19 + exp2 trick): scores arrive in log2 units (log2e
// folded into Q), so softmax uses bare exp2f (1 v_exp, no v_mul). Defer-max
// threshold rescaled to 8*log2(e) = 11.5416 (same e^8 bound on P).
// ---------------------------------------------------------------------------
__global__ __launch_bounds__(256) void attn_fwd5(const u16* __restrict__ Qb,
                                                 const u16* __restrict__ Kb,
                                                 const u16* __restrict__ VTb,
                                                 u16* __restrict__ att) {
  __shared__ u16 Kl[2 * 4096];  // 2 bufs x 8 KB
  __shared__ u16 Vl[2 * 4096];
  const int tid = threadIdx.x;
  const int lane = tid & 63, wid = tid >> 6;
  const int l31 = lane & 31, hi1 = lane >> 5;
  const int L = blockIdx.x + 8 * (blockIdx.y + 12 * blockIdx.z);
  const int bx = 7 - ((L >> 3) & 7);  // heavy (large-bx) blocks first
  const int P = (L & 7) + 8 * (L >> 6);
  const int h = P % 12, b = P / 12;
  const int q0 = bx * 128;
  const int qw0 = q0 + wid * 32;
  const int qg = qw0 + l31;
  const size_t rowbase = (size_t)b * S_;

  // Q fragments (B-operand of swapped QK^T); pre-scaled by 0.125*log2e
  bf16x8 qf[4];
  {
    const u16* qp = Qb + (rowbase + qg) * D_ + h * 64 + hi1 * 8;
#pragma unroll
    for (int c = 0; c < 4; ++c) qf[c] = *(const bf16x8*)(qp + c * 16);
  }
  float mrun = -3.0e38f, lrun = 0.0f;
  f32x16 o0 = {}, o1 = {};

  const u16* kgp =
      Kb + (rowbase + (tid & 31)) * D_ + h * 64 + (tid >> 6) * 16 + ((tid >> 5) & 1) * 8;
  const u16* vgp = VTb +
                   (((size_t)b * H_ + h) * 64 + ((tid >> 6) & 1) * 32 + (tid & 31)) * S_ +
                   (tid >> 7) * 16 + ((tid >> 5) & 1) * 8;
  char* const kdst = (char*)Kl + wid * 1024;
  char* const vdst = (char*)Vl + wid * 1024;
  const char* const kbase = (const char*)Kl + lane * 16;
  const char* const vbase = (const char*)Vl + lane * 16;

  const int T64 = (q0 + 128) >> 6;

  GLD16(kgp, kdst);
  GLD16(kgp + (size_t)32 * D_, kdst + 4096);
  GLD16(vgp, vdst);
  GLD16(vgp + 32, vdst + 4096);
  asm volatile("s_waitcnt vmcnt(0)" ::: "memory");
  __builtin_amdgcn_s_barrier();

  for (int t = 0; t < T64; ++t) {
    if (t + 1 < T64) {
      const int nb = ((t + 1) & 1) * 8192;
      const size_t kvn = (size_t)(t + 1) * 64;
      GLD16(kgp + kvn * D_, kdst + nb);
      GLD16(kgp + (kvn + 32) * D_, kdst + nb + 4096);
      GLD16(vgp + kvn, vdst + nb);
      GLD16(vgp + kvn + 32, vdst + nb + 4096);
    }
#pragma unroll
    for (int sub = 0; sub < 2; ++sub) {
      const int kv0 = t * 64 + sub * 32;
      if (kv0 <= qw0 + 31) {
        const int sb = (t & 1) * 8192 + sub * 4096;
        f32x16 s = {};
#pragma unroll
        for (int c = 0; c < 4; ++c)
          s = MFMA32(*(const bf16x8*)(kbase + sb + c * 1024), qf[c], s);

        if (kv0 + 31 > qw0) {
#pragma unroll
          for (int r = 0; r < 16; ++r) {
            const int kvg = kv0 + (r & 3) + 8 * (r >> 2) + 4 * hi1;
            if (kvg > qg) s[r] = -1.0e30f;
          }
        }
        float rm = s[0];
#pragma unroll
        for (int r = 1; r < 16; ++r) rm = fmaxf(rm, s[r]);
        rm = fmaxf(rm, __shfl_xor(rm, 32));
        // defer-max: THR = 8*log2e (scores are in log2 units)
        if (!__all(rm - mrun <= 11.541561f)) {
          const float mn = fmaxf(mrun, rm);
          const float fr = exp2f(mrun - mn);
          mrun = mn;
          lrun *= fr;
#pragma unroll
          for (int r = 0; r < 16; ++r) {
            o0[r] *= fr;
            o1[r] *= fr;
          }
        }
        float p[16];
        float rs = 0.0f;
#pragma unroll
        for (int r = 0; r < 16; ++r) {
          p[r] = exp2f(s[r] - mrun);  // bare v_exp: log2e pre-folded into Q
          rs += p[r];
        }
        rs += __shfl_xor(rs, 32);
        lrun += rs;
        unsigned int pa[4], pb[4];
#pragma unroll
        for (int g = 0; g < 4; ++g) {
          pa[g] = cvt_pk_bf16(p[4 * g], p[4 * g + 1]);
          pb[g] = cvt_pk_bf16(p[4 * g + 2], p[4 * g + 3]);
        }
        const unsigned sa = __shfl_xor(hi1 ? pa[0] : pa[1], 32);
        const unsigned sbx = __shfl_xor(hi1 ? pb[0] : pb[1], 32);
        const unsigned sc = __shfl_xor(hi1 ? pa[2] : pa[3], 32);
        const unsigned sd = __shfl_xor(hi1 ? pb[2] : pb[3], 32);
        const uint4 w0 =
            hi1 ? make_uint4(sa, sbx, pa[1], pb[1]) : make_uint4(pa[0], pb[0], sa, sbx);
        const uint4 w1 =
            hi1 ? make_uint4(sc, sd, pa[3], pb[3]) : make_uint4(pa[2], pb[2], sc, sd);
        bf16x8 pf0, pf1;
        __builtin_memcpy(&pf0, &w0, 16);
        __builtin_memcpy(&pf1, &w1, 16);
        o0 = MFMA32(*(const bf16x8*)(vbase + sb + 0 * 1024), pf0, o0);
        o1 = MFMA32(*(const bf16x8*)(vbase + sb + 1 * 1024), pf0, o1);
        o0 = MFMA32(*(const bf16x8*)(vbase + sb + 2 * 1024), pf1, o0);
        o1 = MFMA32(*(const bf16x8*)(vbase + sb + 3 * 1024), pf1, o1);
      }
    }
    asm volatile("s_waitcnt vmcnt(0)" ::: "memory");
    __builtin_amdgcn_s_barrier();
  }
  const float inv = 1.0f / lrun;
  u16* op = att + (rowbase + qg) * D_ + h * 64;
#pragma unroll
  for (int g = 0; g < 4; ++g) {
    u16x4 v0, v1;
#pragma unroll
    for (int j = 0; j < 4; ++j) {
      v0[j] = f2bf(o0[4 * g + j] * inv);
      v1[j] = f2bf(o1[4 * g + j] * inv);
    }
    *(u16x4*)(op + 8 * g + 4 * hi1) = v0;
    *(u16x4*)(op + 32 + 8 * g + 4 * hi1) = v1;
  }
}

// ---------------------------------------------------------------------------
extern "C" void kernel_launch(void* const* d_in, const int* in_sizes, int n_in, void* d_out,
                              int out_size, void* d_ws, size_t ws_size, hipStream_t stream) {
  const float *x = nullptr, *Wqkv = nullptr, *bqkv = nullptr, *Wo = nullptr, *bo = nullptr;
  for (int i = 0; i < n_in; ++i) {
    switch (in_sizes[i]) {
      case 16384 * 768:  x = (const float*)d_in[i]; break;
      case 768 * 2304:   Wqkv = (const float*)d_in[i]; break;
      case 2304:         bqkv = (const float*)d_in[i]; break;
      case 768 * 768:    Wo = (const float*)d_in[i]; break;
      case 768:          bo = (const float*)d_in[i]; break;
    }
  }
  float* out = (float*)d_out;  // [16,1024,768] FLOAT32

  char* ws = (char*)d_ws;
  u16* WqkvT = (u16*)(ws);              // 2304*768*2  = 3,538,944
  u16* WoT = (u16*)(ws + 3538944);      // 768*768*2   = 1,179,648
  u16* Qb = (u16*)(ws + 4718592);       // 16384*768*2 = 25,165,824
  u16* Kb = (u16*)(ws + 29884416);      // 25,165,824
  u16* VT = (u16*)(ws + 55050240);      // 25,165,824 -> ws total 80,216,064 B
  u16* xb = (u16*)d_out;  // bf16 x staged in d_out; dead before final GEMM
  u16* att = Qb;          // alias: attn block reads its own Q region first

  prep<<<8448, 256, 0, stream>>>(x, xb, Wqkv, WqkvT, Wo, WoT);
  gemm_bt<0><<<2304, 256, 0, stream>>>(xb, WqkvT, bqkv, Qb, Kb, VT, nullptr,
                                       16384, 2304, 768, 18);
  attn_fwd5<<<dim3(8, H_, B_), 256, 0, stream>>>(Qb, Kb, VT, att);
  gemm_bt<1><<<768, 256, 0, stream>>>(att, WoT, bo, nullptr, nullptr, nullptr, out,
                                      16384, 768, 768, 6);
}

// Round 21
// 218.583 us; speedup vs baseline: 1.0778x; 1.0778x over previous
//
#include <hip/hip_runtime.h>
#include <stdint.h>

typedef unsigned short u16;
typedef __attribute__((ext_vector_type(8))) short bf16x8;
typedef __attribute__((ext_vector_type(8))) u16 u16x8;
typedef __attribute__((ext_vector_type(4))) u16 u16x4;
typedef __attribute__((ext_vector_type(4))) float f32x4;
typedef __attribute__((ext_vector_type(16))) float f32x16;

#define B_ 16
#define S_ 1024
#define D_ 768
#define H_ 12

__device__ __forceinline__ float bf2f(u16 u) {
  unsigned int x = ((unsigned int)u) << 16;
  float f;
  __builtin_memcpy(&f, &x, 4);
  return f;
}
__device__ __forceinline__ u16 f2bf(float f) {
  unsigned int x;
  __builtin_memcpy(&x, &f, 4);
  x += 0x7fffu + ((x >> 16) & 1u);
  return (u16)(x >> 16);
}
__device__ __forceinline__ unsigned cvt_pk_bf16(float lo, float hi) {
  unsigned r;
  asm("v_cvt_pk_bf16_f32 %0, %1, %2" : "=v"(r) : "v"(lo), "v"(hi));
  return r;  // lo -> bits[15:0], hi -> bits[31:16]
}
// Raw v_exp_f32: 2^x in ONE instruction (exp2f lowers to the slow guarded
// OCML path without fast-math -- the r20 regression).
__device__ __forceinline__ float fast_exp2(float x) {
  float r;
  asm("v_exp_f32 %0, %1" : "=v"(r) : "v"(x));
  return r;
}

#define MFMA16(a, b, c) __builtin_amdgcn_mfma_f32_16x16x32_bf16((a), (b), (c), 0, 0, 0)
#define MFMA32(a, b, c) __builtin_amdgcn_mfma_f32_32x32x16_bf16((a), (b), (c), 0, 0, 0)

#define GLD16(g, l)                                              \
  __builtin_amdgcn_global_load_lds(                              \
      (const __attribute__((address_space(1))) void*)(g),        \
      (__attribute__((address_space(3))) void*)(l), 16, 0, 0)

// ---------------------------------------------------------------------------
// Fused prologue: f32->bf16 convert of x + two transpose-convert weights.
// ---------------------------------------------------------------------------
__global__ __launch_bounds__(256) void prep(const float* __restrict__ x,
                                            u16* __restrict__ xb,
                                            const float* __restrict__ Wqkv,
                                            u16* __restrict__ WqkvT,
                                            const float* __restrict__ Wo,
                                            u16* __restrict__ WoT) {
  __shared__ u16 tt[32][33];
  const int gx = blockIdx.x;
  const int tid = threadIdx.x;
  if (gx < 6144) {  // cvt x: 16384*768/8 = 1,572,864 vec8 elems, exact
    const int i = gx * 256 + tid;
    const float4 a = *(const float4*)(x + (size_t)i * 8);
    const float4 b = *(const float4*)(x + (size_t)i * 8 + 4);
    u16x8 o;
    o[0] = f2bf(a.x); o[1] = f2bf(a.y); o[2] = f2bf(a.z); o[3] = f2bf(a.w);
    o[4] = f2bf(b.x); o[5] = f2bf(b.y); o[6] = f2bf(b.z); o[7] = f2bf(b.w);
    *(u16x8*)(xb + (size_t)i * 8) = o;
  } else if (gx < 6144 + 1728) {  // Wqkv [768,2304] -> WqkvT [2304,768]
    const int t = gx - 6144;
    const int n0 = (t % 72) * 32, k0 = (t / 72) * 32;
    const int tx = tid & 31, ty = tid >> 5;
#pragma unroll
    for (int i = 0; i < 32; i += 8)
      tt[ty + i][tx] = f2bf(Wqkv[(size_t)(k0 + ty + i) * 2304 + n0 + tx]);
    __syncthreads();
#pragma unroll
    for (int i = 0; i < 32; i += 8)
      WqkvT[(size_t)(n0 + ty + i) * 768 + k0 + tx] = tt[tx][ty + i];
  } else {  // Wo [768,768] -> WoT [768,768]
    const int t = gx - 7872;
    const int n0 = (t % 24) * 32, k0 = (t / 24) * 32;
    const int tx = tid & 31, ty = tid >> 5;
#pragma unroll
    for (int i = 0; i < 32; i += 8)
      tt[ty + i][tx] = f2bf(Wo[(size_t)(k0 + ty + i) * 768 + n0 + tx]);
    __syncthreads();
#pragma unroll
    for (int i = 0; i < 32; i += 8)
      WoT[(size_t)(n0 + ty + i) * 768 + k0 + tx] = tt[tx][ty + i];
  }
}

// ---------------------------------------------------------------------------
// 128x128x64 MFMA GEMM + XCD-stripe schedule (r16 core, proven fastest).
// MODE 0: QKV epilogue -> Q pre-scaled by 0.125*log2(e) (scores land in
//         log2-units so attention uses bare v_exp), K row-major bf16,
//         V^T [B,H,HS,S] bf16 (u16x4-grouped stores).
// MODE 1: f32 row-major Of[M,N].
// ---------------------------------------------------------------------------
template <int MODE>
__global__ __launch_bounds__(256, 2) void gemm_bt(const u16* __restrict__ A,
                                                  const u16* __restrict__ Bt,
                                                  const float* __restrict__ bias,
                                                  u16* __restrict__ O0, u16* __restrict__ O1,
                                                  u16* __restrict__ O2, float* __restrict__ Of,
                                                  int M, int N, int K, int NBT) {
  __shared__ u16 Al[2 * 128 * 64];  // 2 bufs x 16 KB
  __shared__ u16 Bl[2 * 128 * 64];
  const int tid = threadIdx.x;
  const int wid = tid >> 6, lane = tid & 63;
  const int lo = lane & 15, hi = lane >> 4;
  const int wr = wid >> 1, wc = wid & 1;
  const int bid = blockIdx.x;
  const int xcd = bid & 7, idx = bid >> 3;
  const int mb = xcd * 16 + idx / NBT;
  const int nb = idx % NBT;
  const int m0 = mb * 128, n0 = nb * 128;
  const int T = K >> 6;  // 12

  const int sr = lane >> 3;
  const int kk = ((lane & 7) ^ sr) * 8;  // pre-swizzled k element offset
  const u16* const asrc = A + (size_t)(m0 + wid * 8 + sr) * K + kk;
  const u16* const bsrc = Bt + (size_t)(n0 + wid * 8 + sr) * K + kk;

#define STAGE(kt, buf)                                                          \
  do {                                                                          \
    const size_t _k = (size_t)(kt) * 64;                                        \
    GLD16(asrc + _k, (char*)Al + (buf) * 16384 + (wid) * 1024);                 \
    GLD16(asrc + (size_t)32 * K + _k, (char*)Al + (buf) * 16384 + (wid + 4) * 1024);  \
    GLD16(asrc + (size_t)64 * K + _k, (char*)Al + (buf) * 16384 + (wid + 8) * 1024);  \
    GLD16(asrc + (size_t)96 * K + _k, (char*)Al + (buf) * 16384 + (wid + 12) * 1024); \
    GLD16(bsrc + _k, (char*)Bl + (buf) * 16384 + (wid) * 1024);                 \
    GLD16(bsrc + (size_t)32 * K + _k, (char*)Bl + (buf) * 16384 + (wid + 4) * 1024);  \
    GLD16(bsrc + (size_t)64 * K + _k, (char*)Bl + (buf) * 16384 + (wid + 8) * 1024);  \
    GLD16(bsrc + (size_t)96 * K + _k, (char*)Bl + (buf) * 16384 + (wid + 12) * 1024); \
  } while (0)

  f32x4 acc[4][4] = {};

  STAGE(0, 0);
  asm volatile("s_waitcnt vmcnt(0)" ::: "memory");
  __builtin_amdgcn_s_barrier();

  for (int t = 0; t < T; ++t) {
    if (t + 1 < T) STAGE(t + 1, (t + 1) & 1);
    const int cb = (t & 1) * 16384;
    const int swz = (lo & 7) << 4;
    bf16x8 af[4][2], bfv[4][2];
#pragma unroll
    for (int i = 0; i < 4; ++i)
#pragma unroll
      for (int s = 0; s < 2; ++s)
        af[i][s] = *(const bf16x8*)((const char*)Al + cb + (wr * 64 + i * 16 + lo) * 128 +
                                    ((s * 64 + hi * 16) ^ swz));
#pragma unroll
    for (int j = 0; j < 4; ++j)
#pragma unroll
      for (int s = 0; s < 2; ++s)
        bfv[j][s] = *(const bf16x8*)((const char*)Bl + cb + (wc * 64 + j * 16 + lo) * 128 +
                                     ((s * 64 + hi * 16) ^ swz));
    __builtin_amdgcn_s_setprio(1);
#pragma unroll
    for (int i = 0; i < 4; ++i)
#pragma unroll
      for (int j = 0; j < 4; ++j) {
        acc[i][j] = MFMA16(af[i][0], bfv[j][0], acc[i][j]);
        acc[i][j] = MFMA16(af[i][1], bfv[j][1], acc[i][j]);
      }
    __builtin_amdgcn_s_setprio(0);
    if (t + 1 < T) asm volatile("s_waitcnt vmcnt(0)" ::: "memory");
    __builtin_amdgcn_s_barrier();
  }
#undef STAGE
  // Epilogue. C/D: col = lane&15, row = (lane>>4)*4 + r  [verified m89/m91]
  if (MODE == 0 && n0 >= 2 * D_) {
#pragma unroll
    for (int g = 0; g < 4; ++g) {
      const int n = n0 + wc * 64 + g * 16 + lo;
      const float bv = bias[n];
      const int np = n - 2 * D_;
#pragma unroll
      for (int f = 0; f < 4; ++f) {
        const int m = m0 + wr * 64 + f * 16 + hi * 4;
        u16x4 q;
#pragma unroll
        for (int r = 0; r < 4; ++r) q[r] = f2bf(acc[f][g][r] + bv);
        *(u16x4*)&O2[(((size_t)(m >> 10) * H_ + (np >> 6)) * 64 + (np & 63)) * S_ +
                     (m & 1023)] = q;
      }
    }
  } else {
    // Q region: fold attention scale AND log2(e) so scores are log2-units.
    const bool isQ = (MODE == 0) && (n0 < D_);
    const float sc = isQ ? 0.125f * 1.4426950408889634f : 1.0f;
#pragma unroll
    for (int g = 0; g < 4; ++g) {
      const int n = n0 + wc * 64 + g * 16 + lo;
      const float bv = bias[n] * sc;
#pragma unroll
      for (int f = 0; f < 4; ++f) {
#pragma unroll
        for (int r = 0; r < 4; ++r) {
          const int m = m0 + wr * 64 + f * 16 + hi * 4 + r;
          const float fv = acc[f][g][r] * sc + bv;
          if (MODE == 0) {
            const u16 o = f2bf(fv);
            if (n0 < D_) {
              O0[(size_t)m * D_ + n] = o;  // Q (pre-scaled, log2-units)
            } else {
              O1[(size_t)m * D_ + (n - D_)] = o;  // K row-major
            }
          } else {
            Of[(size_t)m * N + n] = fv;  // f32 output
          }
        }
      }
    }
  }
}

// ---------------------------------------------------------------------------
// Flash attention v6: r19 structure + log2-folded Q + raw v_exp_f32 softmax
// (ONE transcendental per score; r20's exp2f lowered to slow OCML code).
// Defer-max THR = 8*log2(e) = 11.5416 (same e^8 bound on P).
// ---------------------------------------------------------------------------
__global__ __launch_bounds__(256) void attn_fwd6(const u16* __restrict__ Qb,
                                                 const u16* __restrict__ Kb,
                                                 const u16* __restrict__ VTb,
                                                 u16* __restrict__ att) {
  __shared__ u16 Kl[2 * 4096];  // 2 bufs x 8 KB
  __shared__ u16 Vl[2 * 4096];
  const int tid = threadIdx.x;
  const int lane = tid & 63, wid = tid >> 6;
  const int l31 = lane & 31, hi1 = lane >> 5;
  const int L = blockIdx.x + 8 * (blockIdx.y + 12 * blockIdx.z);
  const int bx = 7 - ((L >> 3) & 7);  // heavy (large-bx) blocks first
  const int P = (L & 7) + 8 * (L >> 6);
  const int h = P % 12, b = P / 12;
  const int q0 = bx * 128;
  const int qw0 = q0 + wid * 32;
  const int qg = qw0 + l31;
  const size_t rowbase = (size_t)b * S_;

  // Q fragments (B-operand of swapped QK^T); pre-scaled by 0.125*log2e
  bf16x8 qf[4];
  {
    const u16* qp = Qb + (rowbase + qg) * D_ + h * 64 + hi1 * 8;
#pragma unroll
    for (int c = 0; c < 4; ++c) qf[c] = *(const bf16x8*)(qp + c * 16);
  }
  float mrun = -3.0e38f, lrun = 0.0f;
  f32x16 o0 = {}, o1 = {};

  const u16* kgp =
      Kb + (rowbase + (tid & 31)) * D_ + h * 64 + (tid >> 6) * 16 + ((tid >> 5) & 1) * 8;
  const u16* vgp = VTb +
                   (((size_t)b * H_ + h) * 64 + ((tid >> 6) & 1) * 32 + (tid & 31)) * S_ +
                   (tid >> 7) * 16 + ((tid >> 5) & 1) * 8;
  char* const kdst = (char*)Kl + wid * 1024;
  char* const vdst = (char*)Vl + wid * 1024;
  const char* const kbase = (const char*)Kl + lane * 16;
  const char* const vbase = (const char*)Vl + lane * 16;

  const int T64 = (q0 + 128) >> 6;

  GLD16(kgp, kdst);
  GLD16(kgp + (size_t)32 * D_, kdst + 4096);
  GLD16(vgp, vdst);
  GLD16(vgp + 32, vdst + 4096);
  asm volatile("s_waitcnt vmcnt(0)" ::: "memory");
  __builtin_amdgcn_s_barrier();

  for (int t = 0; t < T64; ++t) {
    if (t + 1 < T64) {
      const int nb = ((t + 1) & 1) * 8192;
      const size_t kvn = (size_t)(t + 1) * 64;
      GLD16(kgp + kvn * D_, kdst + nb);
      GLD16(kgp + (kvn + 32) * D_, kdst + nb + 4096);
      GLD16(vgp + kvn, vdst + nb);
      GLD16(vgp + kvn + 32, vdst + nb + 4096);
    }
#pragma unroll
    for (int sub = 0; sub < 2; ++sub) {
      const int kv0 = t * 64 + sub * 32;
      if (kv0 <= qw0 + 31) {
        const int sb = (t & 1) * 8192 + sub * 4096;
        f32x16 s = {};
#pragma unroll
        for (int c = 0; c < 4; ++c)
          s = MFMA32(*(const bf16x8*)(kbase + sb + c * 1024), qf[c], s);

        if (kv0 + 31 > qw0) {
#pragma unroll
          for (int r = 0; r < 16; ++r) {
            const int kvg = kv0 + (r & 3) + 8 * (r >> 2) + 4 * hi1;
            if (kvg > qg) s[r] = -1.0e30f;
          }
        }
        float rm = s[0];
#pragma unroll
        for (int r = 1; r < 16; ++r) rm = fmaxf(rm, s[r]);
        rm = fmaxf(rm, __shfl_xor(rm, 32));
        // defer-max: THR = 8*log2e (scores are in log2 units)
        if (!__all(rm - mrun <= 11.541561f)) {
          const float mn = fmaxf(mrun, rm);
          const float fr = fast_exp2(mrun - mn);
          mrun = mn;
          lrun *= fr;
#pragma unroll
          for (int r = 0; r < 16; ++r) {
            o0[r] *= fr;
            o1[r] *= fr;
          }
        }
        float p[16];
        float rs = 0.0f;
#pragma unroll
        for (int r = 0; r < 16; ++r) {
          p[r] = fast_exp2(s[r] - mrun);  // single v_exp_f32 per score
          rs += p[r];
        }
        rs += __shfl_xor(rs, 32);
        lrun += rs;
        unsigned int pa[4], pb[4];
#pragma unroll
        for (int g = 0; g < 4; ++g) {
          pa[g] = cvt_pk_bf16(p[4 * g], p[4 * g + 1]);
          pb[g] = cvt_pk_bf16(p[4 * g + 2], p[4 * g + 3]);
        }
        const unsigned sa = __shfl_xor(hi1 ? pa[0] : pa[1], 32);
        const unsigned sbx = __shfl_xor(hi1 ? pb[0] : pb[1], 32);
        const unsigned sc = __shfl_xor(hi1 ? pa[2] : pa[3], 32);
        const unsigned sd = __shfl_xor(hi1 ? pb[2] : pb[3], 32);
        const uint4 w0 =
            hi1 ? make_uint4(sa, sbx, pa[1], pb[1]) : make_uint4(pa[0], pb[0], sa, sbx);
        const uint4 w1 =
            hi1 ? make_uint4(sc, sd, pa[3], pb[3]) : make_uint4(pa[2], pb[2], sc, sd);
        bf16x8 pf0, pf1;
        __builtin_memcpy(&pf0, &w0, 16);
        __builtin_memcpy(&pf1, &w1, 16);
        o0 = MFMA32(*(const bf16x8*)(vbase + sb + 0 * 1024), pf0, o0);
        o1 = MFMA32(*(const bf16x8*)(vbase + sb + 1 * 1024), pf0, o1);
        o0 = MFMA32(*(const bf16x8*)(vbase + sb + 2 * 1024), pf1, o0);
        o1 = MFMA32(*(const bf16x8*)(vbase + sb + 3 * 1024), pf1, o1);
      }
    }
    asm volatile("s_waitcnt vmcnt(0)" ::: "memory");
    __builtin_amdgcn_s_barrier();
  }
  const float inv = 1.0f / lrun;
  u16* op = att + (rowbase + qg) * D_ + h * 64;
#pragma unroll
  for (int g = 0; g < 4; ++g) {
    u16x4 v0, v1;
#pragma unroll
    for (int j = 0; j < 4; ++j) {
      v0[j] = f2bf(o0[4 * g + j] * inv);
      v1[j] = f2bf(o1[4 * g + j] * inv);
    }
    *(u16x4*)(op + 8 * g + 4 * hi1) = v0;
    *(u16x4*)(op + 32 + 8 * g + 4 * hi1) = v1;
  }
}

// ---------------------------------------------------------------------------
extern "C" void kernel_launch(void* const* d_in, const int* in_sizes, int n_in, void* d_out,
                              int out_size, void* d_ws, size_t ws_size, hipStream_t stream) {
  const float *x = nullptr, *Wqkv = nullptr, *bqkv = nullptr, *Wo = nullptr, *bo = nullptr;
  for (int i = 0; i < n_in; ++i) {
    switch (in_sizes[i]) {
      case 16384 * 768:  x = (const float*)d_in[i]; break;
      case 768 * 2304:   Wqkv = (const float*)d_in[i]; break;
      case 2304:         bqkv = (const float*)d_in[i]; break;
      case 768 * 768:    Wo = (const float*)d_in[i]; break;
      case 768:          bo = (const float*)d_in[i]; break;
    }
  }
  float* out = (float*)d_out;  // [16,1024,768] FLOAT32

  char* ws = (char*)d_ws;
  u16* WqkvT = (u16*)(ws);              // 2304*768*2  = 3,538,944
  u16* WoT = (u16*)(ws + 3538944);      // 768*768*2   = 1,179,648
  u16* Qb = (u16*)(ws + 4718592);       // 16384*768*2 = 25,165,824
  u16* Kb = (u16*)(ws + 29884416);      // 25,165,824
  u16* VT = (u16*)(ws + 55050240);      // 25,165,824 -> ws total 80,216,064 B
  u16* xb = (u16*)d_out;  // bf16 x staged in d_out; dead before final GEMM
  u16* att = Qb;          // alias: attn block reads its own Q region first

  prep<<<8448, 256, 0, stream>>>(x, xb, Wqkv, WqkvT, Wo, WoT);
  gemm_bt<0><<<2304, 256, 0, stream>>>(xb, WqkvT, bqkv, Qb, Kb, VT, nullptr,
                                       16384, 2304, 768, 18);
  attn_fwd6<<<dim3(8, H_, B_), 256, 0, stream>>>(Qb, Kb, VT, att);
  gemm_bt<1><<<768, 256, 0, stream>>>(att, WoT, bo, nullptr, nullptr, nullptr, out,
                                      16384, 768, 768, 6);
}